// Round 4
// baseline (7102.589 us; speedup 1.0000x reference)
//
#include <hip/hip_runtime.h>

#define NN 500000
#define NE 4000000
#define FI 24
#define FH 64
#define KC 6
#define FO 6
#define BN_EPS 1e-5f

#define SCAN_BS 256
#define NBLK_SCAN ((NN + SCAN_BS - 1) / SCAN_BS)   // 1954

#define TN 128                                     // nodes per GEMM tile
#define NTILES ((NN + TN - 1) / TN)                // 3907
#define GEMM_GRID 1024

// ---------------- small helpers ----------------

__device__ __forceinline__ void fma4(float4& a, float s, const float4 v) {
    a.x += s * v.x; a.y += s * v.y; a.z += s * v.z; a.w += s * v.w;
}
__device__ __forceinline__ void add4(float4& a, const float4 v) {
    a.x += v.x; a.y += v.y; a.z += v.z; a.w += v.w;
}

// ---------------- degree ----------------

__global__ void k_deg(const int* __restrict__ col, int* __restrict__ deg) {
    int e = blockIdx.x * blockDim.x + threadIdx.x;
    if (e < NE) atomicAdd(&deg[col[e]], 1);
}

__global__ void k_dis(const int* __restrict__ deg, float* __restrict__ dis) {
    int i = blockIdx.x * blockDim.x + threadIdx.x;
    if (i < NN) {
        int d = deg[i];
        dis[i] = d > 0 ? rsqrtf((float)d) : 0.0f;
    }
}

// ---------------- exclusive scan over deg -> rp (3 phase) ----------------

__global__ void k_scanA(const int* __restrict__ deg, int* __restrict__ partials) {
    __shared__ int lds[SCAN_BS];
    int i = blockIdx.x * SCAN_BS + threadIdx.x;
    lds[threadIdx.x] = (i < NN) ? deg[i] : 0;
    __syncthreads();
    for (int s = SCAN_BS / 2; s > 0; s >>= 1) {
        if (threadIdx.x < s) lds[threadIdx.x] += lds[threadIdx.x + s];
        __syncthreads();
    }
    if (threadIdx.x == 0) partials[blockIdx.x] = lds[0];
}

__global__ void k_scanB(int* __restrict__ partials, int n) {
    __shared__ int tsum[256];
    int vals[8];
    int base = threadIdx.x * 8;
    int acc = 0;
    #pragma unroll
    for (int j = 0; j < 8; ++j) {
        int idx = base + j;
        int v = (idx < n) ? partials[idx] : 0;
        vals[j] = acc;
        acc += v;
    }
    tsum[threadIdx.x] = acc;
    __syncthreads();
    int t = acc;
    for (int s = 1; s < 256; s <<= 1) {
        int other = (threadIdx.x >= (unsigned)s) ? tsum[threadIdx.x - s] : 0;
        __syncthreads();
        t += other;
        tsum[threadIdx.x] = t;
        __syncthreads();
    }
    int prefix = (threadIdx.x == 0) ? 0 : tsum[threadIdx.x - 1];
    #pragma unroll
    for (int j = 0; j < 8; ++j) {
        int idx = base + j;
        if (idx < n) partials[idx] = prefix + vals[j];
    }
}

__global__ void k_scanC(const int* __restrict__ deg, const int* __restrict__ partials,
                        int* __restrict__ rp) {
    __shared__ int lds[SCAN_BS];
    int i = blockIdx.x * SCAN_BS + threadIdx.x;
    int v = (i < NN) ? deg[i] : 0;
    lds[threadIdx.x] = v;
    __syncthreads();
    int t = v;
    for (int s = 1; s < SCAN_BS; s <<= 1) {
        int other = (threadIdx.x >= (unsigned)s) ? lds[threadIdx.x - s] : 0;
        __syncthreads();
        t += other;
        lds[threadIdx.x] = t;
        __syncthreads();
    }
    int excl = t - v + partials[blockIdx.x];
    if (i < NN) rp[i] = excl;
    if (i == NN - 1) rp[NN] = excl + v;   // total == NE
}

// ---------------- CSR fill ----------------

__global__ void k_fill(const int* __restrict__ row, const int* __restrict__ col,
                       const int* __restrict__ rp, int* __restrict__ fill,
                       int* __restrict__ csrc) {
    int e = blockIdx.x * blockDim.x + threadIdx.x;
    if (e >= NE) return;
    int r = row[e], c = col[e];
    int pos = rp[c] + atomicAdd(&fill[c], 1);
    csrc[pos] = r;
}

// ---------------- propagation: Tout = (FIRST ? P : 2P - Tpp) ----------------
// P_c = -dis_c * sum_{e into c} dis_r * Tin[r]; 2 thr/node, 2-edge unroll for MLP

template<bool FIRST>
__global__ __launch_bounds__(256) void k_prop(
    const int* __restrict__ rp, const int* __restrict__ csrc,
    const float* __restrict__ dis,
    const float* __restrict__ Tin, const float* __restrict__ Tpp,
    float* __restrict__ Tout) {
    int t = blockIdx.x * 256 + threadIdx.x;
    int n = t >> 1, q = t & 1;
    if (n >= NN) return;
    int beg = rp[n], end = rp[n + 1];
    const float4* Tg = (const float4*)Tin;
    float4 a0 = make_float4(0.f, 0.f, 0.f, 0.f), a1 = a0, a2 = a0;
    float4 b0 = a0, b1 = a0, b2 = a0;
    int i = beg;
    for (; i + 2 <= end; i += 2) {
        int s0 = csrc[i], s1 = csrc[i + 1];
        float d0 = dis[s0], d1 = dis[s1];
        const float4* r0 = Tg + (size_t)s0 * 6 + q * 3;
        const float4* r1 = Tg + (size_t)s1 * 6 + q * 3;
        float4 v00 = r0[0], v01 = r0[1], v02 = r0[2];
        float4 v10 = r1[0], v11 = r1[1], v12 = r1[2];
        fma4(a0, d0, v00); fma4(a1, d0, v01); fma4(a2, d0, v02);
        fma4(b0, d1, v10); fma4(b1, d1, v11); fma4(b2, d1, v12);
    }
    if (i < end) {
        int s0 = csrc[i];
        float d0 = dis[s0];
        const float4* r0 = Tg + (size_t)s0 * 6 + q * 3;
        fma4(a0, d0, r0[0]); fma4(a1, d0, r0[1]); fma4(a2, d0, r0[2]);
    }
    add4(a0, b0); add4(a1, b1); add4(a2, b2);
    float m = -dis[n];
    size_t ob = (size_t)n * 6 + q * 3;
    float4* O4 = (float4*)Tout;
    if (FIRST) {
        O4[ob + 0] = make_float4(m * a0.x, m * a0.y, m * a0.z, m * a0.w);
        O4[ob + 1] = make_float4(m * a1.x, m * a1.y, m * a1.z, m * a1.w);
        O4[ob + 2] = make_float4(m * a2.x, m * a2.y, m * a2.z, m * a2.w);
    } else {
        const float4* P4 = (const float4*)Tpp;
        float4 p0 = P4[ob + 0], p1 = P4[ob + 1], p2 = P4[ob + 2];
        float tm = 2.0f * m;
        O4[ob + 0] = make_float4(tm * a0.x - p0.x, tm * a0.y - p0.y, tm * a0.z - p0.z, tm * a0.w - p0.w);
        O4[ob + 1] = make_float4(tm * a1.x - p1.x, tm * a1.y - p1.y, tm * a1.z - p1.z, tm * a1.w - p1.w);
        O4[ob + 2] = make_float4(tm * a2.x - p2.x, tm * a2.y - p2.y, tm * a2.z - p2.z, tm * a2.w - p2.w);
    }
}

// ---------------- GEMM core v2: direct global X loads (L1 broadcast), W in LDS ----------------
// Block 256 thr, persistent over tiles. Thread (ng=tid>>4, fg=tid&15) owns
// nodes {n0+ng+16j, j<8} x feats {fg*4..fg*4+3}. No syncthreads in the loop.
// rowb[j] is clamped to NN-1 so all loads are in-bounds; valid[] masks epilogue.

#define GEMM_CORE_V2                                                                \
    size_t rowb[8];                                                                 \
    _Pragma("unroll")                                                               \
    for (int j = 0; j < 8; ++j) {                                                   \
        int node = n0 + ng + 16 * j;                                                \
        rowb[j] = (size_t)(node < NN ? node : NN - 1) * FI;                         \
    }                                                                               \
    float acc[8][4];                                                                \
    _Pragma("unroll")                                                               \
    for (int j = 0; j < 8; ++j) {                                                   \
        acc[j][0] = bb.x; acc[j][1] = bb.y; acc[j][2] = bb.z; acc[j][3] = bb.w;     \
    }                                                                               \
    _Pragma("unroll")                                                               \
    for (int seg = 0; seg < KC; ++seg) {                                            \
        const float* srcp = (seg == 0) ? x : (Tbase + (size_t)(seg - 1) * ((size_t)NN * FI)); \
        _Pragma("unroll")                                                           \
        for (int g = 0; g < 6; ++g) {                                               \
            const int kk = g * 4;                                                   \
            float4 w0 = *(const float4*)&Wl[(seg * 24 + kk + 0) * FH + fg * 4];     \
            float4 w1 = *(const float4*)&Wl[(seg * 24 + kk + 1) * FH + fg * 4];     \
            float4 w2 = *(const float4*)&Wl[(seg * 24 + kk + 2) * FH + fg * 4];     \
            float4 w3 = *(const float4*)&Wl[(seg * 24 + kk + 3) * FH + fg * 4];     \
            _Pragma("unroll")                                                       \
            for (int j = 0; j < 8; ++j) {                                           \
                float4 xv = *(const float4*)&srcp[rowb[j] + kk];                    \
                acc[j][0] += xv.x * w0.x + xv.y * w1.x + xv.z * w2.x + xv.w * w3.x; \
                acc[j][1] += xv.x * w0.y + xv.y * w1.y + xv.z * w2.y + xv.w * w3.y; \
                acc[j][2] += xv.x * w0.z + xv.y * w1.z + xv.z * w2.z + xv.w * w3.z; \
                acc[j][3] += xv.x * w0.w + xv.y * w1.w + xv.z * w2.w + xv.w * w3.w; \
            }                                                                       \
        }                                                                           \
    }

// ---------------- pass 1: BN stats of h (h not stored) ----------------

__global__ __launch_bounds__(256) void k_pass1(
    const float* __restrict__ x, const float* __restrict__ Tbase,
    const float* __restrict__ W1, const float* __restrict__ b1,
    float* __restrict__ stats) {
    __shared__ float Wl[KC * FI * FH];   // 36 KiB
    __shared__ float st[2 * FH];
    {
        const float4* src = (const float4*)W1;
        float4* dst = (float4*)Wl;
        for (int i = threadIdx.x; i < KC * FI * FH / 4; i += 256) dst[i] = src[i];
    }
    if (threadIdx.x < 2 * FH) st[threadIdx.x] = 0.0f;
    __syncthreads();
    const int fg = threadIdx.x & 15;
    const int ng = threadIdx.x >> 4;
    const float4 bb = *(const float4*)&b1[fg * 4];
    float ssum[4] = {0, 0, 0, 0}, sqsum[4] = {0, 0, 0, 0};
    for (int tile = blockIdx.x; tile < NTILES; tile += gridDim.x) {
        const int n0 = tile * TN;
        GEMM_CORE_V2
        #pragma unroll
        for (int j = 0; j < 8; ++j) {
            if (n0 + ng + 16 * j < NN) {
                #pragma unroll
                for (int c = 0; c < 4; ++c) {
                    float v = acc[j][c];
                    ssum[c] += v;
                    sqsum[c] += v * v;
                }
            }
        }
    }
    #pragma unroll
    for (int c = 0; c < 4; ++c) {
        atomicAdd(&st[fg * 4 + c], ssum[c]);
        atomicAdd(&st[FH + fg * 4 + c], sqsum[c]);
    }
    __syncthreads();
    if (threadIdx.x < 2 * FH) atomicAdd(&stats[threadIdx.x], st[threadIdx.x]);
}

// ---------------- BN finalize ----------------

__global__ void k_finalize(const float* __restrict__ stats, const float* __restrict__ gamma,
                           const float* __restrict__ beta, float* __restrict__ ss) {
    int f = threadIdx.x;
    if (f < FH) {
        float mean = stats[f] * (1.0f / NN);
        float var  = stats[f + FH] * (1.0f / NN) - mean * mean;
        float rstd = rsqrtf(var + BN_EPS);
        float sc = gamma[f] * rstd;
        ss[f] = sc;
        ss[f + FH] = beta[f] - mean * sc;
    }
}

// ---------------- pass 2: recompute h, fused BN+ReLU+mix -> y ----------------

__global__ __launch_bounds__(256) void k_pass2(
    const float* __restrict__ x, const float* __restrict__ Tbase,
    const float* __restrict__ W1, const float* __restrict__ b1,
    const float* __restrict__ ss,
    const float* __restrict__ Wmix, const float* __restrict__ bmix,
    float* __restrict__ y) {
    __shared__ float Wl[KC * FI * FH];
    {
        const float4* src = (const float4*)W1;
        float4* dst = (float4*)Wl;
        for (int i = threadIdx.x; i < KC * FI * FH / 4; i += 256) dst[i] = src[i];
    }
    __syncthreads();
    const int fg = threadIdx.x & 15;
    const int ng = threadIdx.x >> 4;
    const float4 bb  = *(const float4*)&b1[fg * 4];
    const float4 scv = *(const float4*)&ss[fg * 4];
    const float4 shv = *(const float4*)&ss[FH + fg * 4];
    float wm[4][FO];
    #pragma unroll
    for (int c = 0; c < 4; ++c)
        #pragma unroll
        for (int o = 0; o < FO; ++o) wm[c][o] = Wmix[(fg * 4 + c) * FO + o];
    float bm[FO];
    #pragma unroll
    for (int o = 0; o < FO; ++o) bm[o] = bmix[o];

    for (int tile = blockIdx.x; tile < NTILES; tile += gridDim.x) {
        const int n0 = tile * TN;
        GEMM_CORE_V2
        // epilogue: BN + ReLU + partial mix
        float p[8][FO];
        #pragma unroll
        for (int j = 0; j < 8; ++j) {
            float h0 = fmaxf(acc[j][0] * scv.x + shv.x, 0.0f);
            float h1 = fmaxf(acc[j][1] * scv.y + shv.y, 0.0f);
            float h2 = fmaxf(acc[j][2] * scv.z + shv.z, 0.0f);
            float h3 = fmaxf(acc[j][3] * scv.w + shv.w, 0.0f);
            #pragma unroll
            for (int o = 0; o < FO; ++o)
                p[j][o] = h0 * wm[0][o] + h1 * wm[1][o] + h2 * wm[2][o] + h3 * wm[3][o];
        }
        // reduce across the 16 fg lanes (lane bits 0..3)
        #pragma unroll
        for (int m = 1; m < 16; m <<= 1) {
            #pragma unroll
            for (int j = 0; j < 8; ++j)
                #pragma unroll
                for (int o = 0; o < FO; ++o)
                    p[j][o] += __shfl_xor(p[j][o], m);
        }
        if (fg == 0) {
            #pragma unroll
            for (int j = 0; j < 8; ++j) {
                int node = n0 + ng + 16 * j;
                if (node < NN) {
                    #pragma unroll
                    for (int o = 0; o < FO; ++o)
                        y[(size_t)node * FO + o] = p[j][o] + bm[o];
                }
            }
        }
    }
}

// ---------------- launch ----------------

extern "C" void kernel_launch(void* const* d_in, const int* in_sizes, int n_in,
                              void* d_out, int out_size, void* d_ws, size_t ws_size,
                              hipStream_t stream) {
    const float* x     = (const float*)d_in[0];
    const int*   edge  = (const int*)d_in[1];   // [2, NE]: row = edge, col = edge+NE
    const float* W1    = (const float*)d_in[2]; // [6,24,64]
    const float* b1    = (const float*)d_in[3];
    const float* gamma = (const float*)d_in[4];
    const float* beta  = (const float*)d_in[5];
    const float* Wmix  = (const float*)d_in[6]; // [1,64,6]
    const float* bmix  = (const float*)d_in[7];
    float* y = (float*)d_out;

    const int* row = edge;
    const int* col = edge + NE;

    // workspace layout (element offsets, 4B units)
    const size_t O_DEG   = 0;                        // NN
    const size_t O_DIS   = 500000;                   // NN
    const size_t O_RP    = 1000000;                  // NN+1 (padded)
    const size_t O_FILL  = 1500008;                  // NN
    const size_t O_PART  = 2000008;                  // 2048
    const size_t O_STATS = 2002056;                  // 128
    const size_t O_SS    = 2002184;                  // 128
    const size_t O_CSRC  = 2002312;                  // NE
    const size_t O_T     = 6002312;                  // 5 * NN*FI
    const size_t TOTAL_ELEMS = O_T + 5ull * NN * FI; // 66,002,312 -> 264 MB
    if (ws_size < TOTAL_ELEMS * 4ull) return;        // clean diagnostic bail

    float* wf = (float*)d_ws;
    int*   wi = (int*)d_ws;
    int*   deg   = wi + O_DEG;
    float* dis   = wf + O_DIS;
    int*   rp    = wi + O_RP;
    int*   fill  = wi + O_FILL;
    int*   part  = wi + O_PART;
    float* stats = wf + O_STATS;
    float* ss    = wf + O_SS;
    int*   csrc  = wi + O_CSRC;
    float* T1    = wf + O_T;
    float* T2    = T1 + (size_t)NN * FI;
    float* T3    = T2 + (size_t)NN * FI;
    float* T4    = T3 + (size_t)NN * FI;
    float* T5    = T4 + (size_t)NN * FI;

    hipMemsetAsync(deg,   0, NN * sizeof(int), stream);
    hipMemsetAsync(fill,  0, NN * sizeof(int), stream);
    hipMemsetAsync(stats, 0, 128 * sizeof(float), stream);

    const int BS = 256;
    k_deg<<<(NE + BS - 1) / BS, BS, 0, stream>>>(col, deg);
    k_dis<<<(NN + BS - 1) / BS, BS, 0, stream>>>(deg, dis);
    k_scanA<<<NBLK_SCAN, SCAN_BS, 0, stream>>>(deg, part);
    k_scanB<<<1, 256, 0, stream>>>(part, NBLK_SCAN);
    k_scanC<<<NBLK_SCAN, SCAN_BS, 0, stream>>>(deg, part, rp);
    k_fill<<<(NE + BS - 1) / BS, BS, 0, stream>>>(row, col, rp, fill, csrc);

    const int GPROP = (NN * 2 + BS - 1) / BS;   // 3907
    k_prop<true ><<<GPROP, BS, 0, stream>>>(rp, csrc, dis, x,  nullptr, T1);
    k_prop<false><<<GPROP, BS, 0, stream>>>(rp, csrc, dis, T1, x,  T2);
    k_prop<false><<<GPROP, BS, 0, stream>>>(rp, csrc, dis, T2, T1, T3);
    k_prop<false><<<GPROP, BS, 0, stream>>>(rp, csrc, dis, T3, T2, T4);
    k_prop<false><<<GPROP, BS, 0, stream>>>(rp, csrc, dis, T4, T3, T5);

    k_pass1<<<GEMM_GRID, 256, 0, stream>>>(x, T1, W1, b1, stats);
    k_finalize<<<1, 64, 0, stream>>>(stats, gamma, beta, ss);
    k_pass2<<<GEMM_GRID, 256, 0, stream>>>(x, T1, W1, b1, ss, Wmix, bmix, y);
}

// Round 5
// 1812.796 us; speedup vs baseline: 3.9180x; 3.9180x over previous
//
#include <hip/hip_runtime.h>

#define NN 500000
#define NE 4000000
#define FI 24
#define FH 64
#define KC 6
#define FO 6
#define BN_EPS 1e-5f

#define SCAN_BS 256
#define NBLK_SCAN ((NN + SCAN_BS - 1) / SCAN_BS)   // 1954

#define TN 128                                     // nodes per GEMM tile
#define PADX 28                                    // Xs row stride; 28%4==0 (b128-aligned), quads disjoint mod 32
#define NTILES ((NN + TN - 1) / TN)                // 3907
#define GEMM_GRID 768

// ---------------- small helpers ----------------

__device__ __forceinline__ void fma4(float4& a, float s, const float4 v) {
    a.x += s * v.x; a.y += s * v.y; a.z += s * v.z; a.w += s * v.w;
}
__device__ __forceinline__ void add4(float4& a, const float4 v) {
    a.x += v.x; a.y += v.y; a.z += v.z; a.w += v.w;
}

// ---------------- degree ----------------

__global__ void k_deg(const int* __restrict__ col, int* __restrict__ deg) {
    int e = blockIdx.x * blockDim.x + threadIdx.x;
    if (e < NE) atomicAdd(&deg[col[e]], 1);
}

__global__ void k_dis(const int* __restrict__ deg, float* __restrict__ dis) {
    int i = blockIdx.x * blockDim.x + threadIdx.x;
    if (i < NN) {
        int d = deg[i];
        dis[i] = d > 0 ? rsqrtf((float)d) : 0.0f;
    }
}

// ---------------- exclusive scan over deg -> rp (3 phase) ----------------

__global__ void k_scanA(const int* __restrict__ deg, int* __restrict__ partials) {
    __shared__ int lds[SCAN_BS];
    int i = blockIdx.x * SCAN_BS + threadIdx.x;
    lds[threadIdx.x] = (i < NN) ? deg[i] : 0;
    __syncthreads();
    for (int s = SCAN_BS / 2; s > 0; s >>= 1) {
        if (threadIdx.x < s) lds[threadIdx.x] += lds[threadIdx.x + s];
        __syncthreads();
    }
    if (threadIdx.x == 0) partials[blockIdx.x] = lds[0];
}

__global__ void k_scanB(int* __restrict__ partials, int n) {
    __shared__ int tsum[256];
    int vals[8];
    int base = threadIdx.x * 8;
    int acc = 0;
    #pragma unroll
    for (int j = 0; j < 8; ++j) {
        int idx = base + j;
        int v = (idx < n) ? partials[idx] : 0;
        vals[j] = acc;
        acc += v;
    }
    tsum[threadIdx.x] = acc;
    __syncthreads();
    int t = acc;
    for (int s = 1; s < 256; s <<= 1) {
        int other = (threadIdx.x >= (unsigned)s) ? tsum[threadIdx.x - s] : 0;
        __syncthreads();
        t += other;
        tsum[threadIdx.x] = t;
        __syncthreads();
    }
    int prefix = (threadIdx.x == 0) ? 0 : tsum[threadIdx.x - 1];
    #pragma unroll
    for (int j = 0; j < 8; ++j) {
        int idx = base + j;
        if (idx < n) partials[idx] = prefix + vals[j];
    }
}

__global__ void k_scanC(const int* __restrict__ deg, const int* __restrict__ partials,
                        int* __restrict__ rp) {
    __shared__ int lds[SCAN_BS];
    int i = blockIdx.x * SCAN_BS + threadIdx.x;
    int v = (i < NN) ? deg[i] : 0;
    lds[threadIdx.x] = v;
    __syncthreads();
    int t = v;
    for (int s = 1; s < SCAN_BS; s <<= 1) {
        int other = (threadIdx.x >= (unsigned)s) ? lds[threadIdx.x - s] : 0;
        __syncthreads();
        t += other;
        lds[threadIdx.x] = t;
        __syncthreads();
    }
    int excl = t - v + partials[blockIdx.x];
    if (i < NN) rp[i] = excl;
    if (i == NN - 1) rp[NN] = excl + v;   // total == NE
}

// ---------------- CSR fill ----------------

__global__ void k_fill(const int* __restrict__ row, const int* __restrict__ col,
                       const int* __restrict__ rp, int* __restrict__ fill,
                       int* __restrict__ csrc) {
    int e = blockIdx.x * blockDim.x + threadIdx.x;
    if (e >= NE) return;
    int r = row[e], c = col[e];
    int pos = rp[c] + atomicAdd(&fill[c], 1);
    csrc[pos] = r;
}

// ---------------- propagation: Tout = (FIRST ? P : 2P - Tpp) ----------------
// P_c = -dis_c * sum_{e into c} dis_r * Tin[r]; 2 thr/node, 4-edge unroll (12 loads in flight)

template<bool FIRST>
__global__ __launch_bounds__(256) void k_prop(
    const int* __restrict__ rp, const int* __restrict__ csrc,
    const float* __restrict__ dis,
    const float* __restrict__ Tin, const float* __restrict__ Tpp,
    float* __restrict__ Tout) {
    int t = blockIdx.x * 256 + threadIdx.x;
    int n = t >> 1, q = t & 1;
    if (n >= NN) return;
    int beg = rp[n], end = rp[n + 1];
    const float4* Tg = (const float4*)Tin + q * 3;   // q-half base
    float4 a0 = make_float4(0.f, 0.f, 0.f, 0.f), a1 = a0, a2 = a0;
    float4 b0 = a0, b1 = a0, b2 = a0;
    int i = beg;
    for (; i + 4 <= end; i += 4) {
        int s0 = csrc[i], s1 = csrc[i + 1], s2 = csrc[i + 2], s3 = csrc[i + 3];
        float d0 = dis[s0], d1 = dis[s1], d2 = dis[s2], d3 = dis[s3];
        const float4* r0 = Tg + (size_t)s0 * 6;
        const float4* r1 = Tg + (size_t)s1 * 6;
        const float4* r2 = Tg + (size_t)s2 * 6;
        const float4* r3 = Tg + (size_t)s3 * 6;
        float4 v00 = r0[0], v01 = r0[1], v02 = r0[2];
        float4 v10 = r1[0], v11 = r1[1], v12 = r1[2];
        float4 v20 = r2[0], v21 = r2[1], v22 = r2[2];
        float4 v30 = r3[0], v31 = r3[1], v32 = r3[2];
        fma4(a0, d0, v00); fma4(a1, d0, v01); fma4(a2, d0, v02);
        fma4(b0, d1, v10); fma4(b1, d1, v11); fma4(b2, d1, v12);
        fma4(a0, d2, v20); fma4(a1, d2, v21); fma4(a2, d2, v22);
        fma4(b0, d3, v30); fma4(b1, d3, v31); fma4(b2, d3, v32);
    }
    for (; i < end; ++i) {
        int s0 = csrc[i];
        float d0 = dis[s0];
        const float4* r0 = Tg + (size_t)s0 * 6;
        fma4(a0, d0, r0[0]); fma4(a1, d0, r0[1]); fma4(a2, d0, r0[2]);
    }
    add4(a0, b0); add4(a1, b1); add4(a2, b2);
    float m = -dis[n];
    size_t ob = (size_t)n * 6 + q * 3;
    float4* O4 = (float4*)Tout;
    if (FIRST) {
        O4[ob + 0] = make_float4(m * a0.x, m * a0.y, m * a0.z, m * a0.w);
        O4[ob + 1] = make_float4(m * a1.x, m * a1.y, m * a1.z, m * a1.w);
        O4[ob + 2] = make_float4(m * a2.x, m * a2.y, m * a2.z, m * a2.w);
    } else {
        const float4* P4 = (const float4*)Tpp;
        float4 p0 = P4[ob + 0], p1 = P4[ob + 1], p2 = P4[ob + 2];
        float tm = 2.0f * m;
        O4[ob + 0] = make_float4(tm * a0.x - p0.x, tm * a0.y - p0.y, tm * a0.z - p0.z, tm * a0.w - p0.w);
        O4[ob + 1] = make_float4(tm * a1.x - p1.x, tm * a1.y - p1.y, tm * a1.z - p1.z, tm * a1.w - p1.w);
        O4[ob + 2] = make_float4(tm * a2.x - p2.x, tm * a2.y - p2.y, tm * a2.z - p2.z, tm * a2.w - p2.w);
    }
}

// ---------------- tiled GEMM core v3 (round-3 structure + b128 staging + SW pipeline) ----
// Block 256 thr; tile 128 nodes x 64 feats; thread (ng=tid>>4, fg=tid&15) owns
// nodes {ng+16j, j<8} x feats {fg*4..+3}. Xs staged per 24-col segment with
// float4 writes; next segment's global loads issued before current compute.

#define GEMM_CORE_V3                                                                \
    float acc[8][4];                                                                \
    _Pragma("unroll")                                                               \
    for (int j = 0; j < 8; ++j) {                                                   \
        acc[j][0] = bb.x; acc[j][1] = bb.y; acc[j][2] = bb.z; acc[j][3] = bb.w;     \
    }                                                                               \
    int snl[3]; int sc4[3]; float4 stg[3];                                          \
    _Pragma("unroll")                                                               \
    for (int i = 0; i < 3; ++i) {                                                   \
        int g4 = threadIdx.x + i * 256;                                             \
        snl[i] = g4 / 6; sc4[i] = g4 - snl[i] * 6;                                  \
    }                                                                               \
    {   /* preload seg 0 (= x) */                                                   \
        const float4* s4 = (const float4*)x + (size_t)n0 * 6;                       \
        _Pragma("unroll")                                                           \
        for (int i = 0; i < 3; ++i) {                                               \
            float4 v = make_float4(0.f, 0.f, 0.f, 0.f);                             \
            if (n0 + snl[i] < NN) v = s4[threadIdx.x + i * 256];                    \
            stg[i] = v;                                                             \
        }                                                                           \
    }                                                                               \
    for (int seg = 0; seg < KC; ++seg) {                                            \
        __syncthreads();                                                            \
        _Pragma("unroll")                                                           \
        for (int i = 0; i < 3; ++i)                                                 \
            *(float4*)&Xs[snl[i] * PADX + sc4[i] * 4] = stg[i];                     \
        __syncthreads();                                                            \
        if (seg + 1 < KC) {  /* issue next seg's loads under this seg's compute */  \
            const float4* s4 = (const float4*)(Tbase + (size_t)seg * ((size_t)NN * FI)) \
                               + (size_t)n0 * 6;                                    \
            _Pragma("unroll")                                                       \
            for (int i = 0; i < 3; ++i) {                                           \
                float4 v = make_float4(0.f, 0.f, 0.f, 0.f);                         \
                if (n0 + snl[i] < NN) v = s4[threadIdx.x + i * 256];                \
                stg[i] = v;                                                         \
            }                                                                       \
        }                                                                           \
        _Pragma("unroll")                                                           \
        for (int g = 0; g < 6; ++g) {                                               \
            const int kk = g * 4;                                                   \
            float4 w0 = *(const float4*)&Wl[(seg * 24 + kk + 0) * FH + fg * 4];     \
            float4 w1 = *(const float4*)&Wl[(seg * 24 + kk + 1) * FH + fg * 4];     \
            float4 w2 = *(const float4*)&Wl[(seg * 24 + kk + 2) * FH + fg * 4];     \
            float4 w3 = *(const float4*)&Wl[(seg * 24 + kk + 3) * FH + fg * 4];     \
            _Pragma("unroll")                                                       \
            for (int j = 0; j < 8; ++j) {                                           \
                float4 xv = *(const float4*)&Xs[(ng + 16 * j) * PADX + kk];         \
                acc[j][0] += xv.x * w0.x + xv.y * w1.x + xv.z * w2.x + xv.w * w3.x; \
                acc[j][1] += xv.x * w0.y + xv.y * w1.y + xv.z * w2.y + xv.w * w3.y; \
                acc[j][2] += xv.x * w0.z + xv.y * w1.z + xv.z * w2.z + xv.w * w3.z; \
                acc[j][3] += xv.x * w0.w + xv.y * w1.w + xv.z * w2.w + xv.w * w3.w; \
            }                                                                       \
        }                                                                           \
    }

// ---------------- pass 1: BN stats of h (h not stored) ----------------

__global__ __launch_bounds__(256) void k_pass1(
    const float* __restrict__ x, const float* __restrict__ Tbase,
    const float* __restrict__ W1, const float* __restrict__ b1,
    float* __restrict__ stats) {
    __shared__ float Wl[KC * FI * FH];   // 36 KiB
    __shared__ float Xs[TN * PADX];      // 14 KiB
    __shared__ float st[2 * FH];
    {
        const float4* src = (const float4*)W1;
        float4* dst = (float4*)Wl;
        for (int i = threadIdx.x; i < KC * FI * FH / 4; i += 256) dst[i] = src[i];
    }
    if (threadIdx.x < 2 * FH) st[threadIdx.x] = 0.0f;
    __syncthreads();
    const int fg = threadIdx.x & 15;
    const int ng = threadIdx.x >> 4;
    const float4 bb = *(const float4*)&b1[fg * 4];
    float ssum[4] = {0, 0, 0, 0}, sqsum[4] = {0, 0, 0, 0};
    for (int tile = blockIdx.x; tile < NTILES; tile += gridDim.x) {
        const int n0 = tile * TN;
        GEMM_CORE_V3
        #pragma unroll
        for (int j = 0; j < 8; ++j) {
            if (n0 + ng + 16 * j < NN) {
                #pragma unroll
                for (int c = 0; c < 4; ++c) {
                    float v = acc[j][c];
                    ssum[c] += v;
                    sqsum[c] += v * v;
                }
            }
        }
    }
    #pragma unroll
    for (int c = 0; c < 4; ++c) {
        atomicAdd(&st[fg * 4 + c], ssum[c]);
        atomicAdd(&st[FH + fg * 4 + c], sqsum[c]);
    }
    __syncthreads();
    if (threadIdx.x < 2 * FH) atomicAdd(&stats[threadIdx.x], st[threadIdx.x]);
}

// ---------------- BN finalize ----------------

__global__ void k_finalize(const float* __restrict__ stats, const float* __restrict__ gamma,
                           const float* __restrict__ beta, float* __restrict__ ss) {
    int f = threadIdx.x;
    if (f < FH) {
        float mean = stats[f] * (1.0f / NN);
        float var  = stats[f + FH] * (1.0f / NN) - mean * mean;
        float rstd = rsqrtf(var + BN_EPS);
        float sc = gamma[f] * rstd;
        ss[f] = sc;
        ss[f + FH] = beta[f] - mean * sc;
    }
}

// ---------------- pass 2: recompute h, fused BN+ReLU+mix -> y ----------------

__global__ __launch_bounds__(256) void k_pass2(
    const float* __restrict__ x, const float* __restrict__ Tbase,
    const float* __restrict__ W1, const float* __restrict__ b1,
    const float* __restrict__ ss,
    const float* __restrict__ Wmix, const float* __restrict__ bmix,
    float* __restrict__ y) {
    __shared__ float Wl[KC * FI * FH];
    __shared__ float Xs[TN * PADX];
    {
        const float4* src = (const float4*)W1;
        float4* dst = (float4*)Wl;
        for (int i = threadIdx.x; i < KC * FI * FH / 4; i += 256) dst[i] = src[i];
    }
    __syncthreads();
    const int fg = threadIdx.x & 15;
    const int ng = threadIdx.x >> 4;
    const float4 bb  = *(const float4*)&b1[fg * 4];
    const float4 scv = *(const float4*)&ss[fg * 4];
    const float4 shv = *(const float4*)&ss[FH + fg * 4];
    float wm[4][FO];
    #pragma unroll
    for (int c = 0; c < 4; ++c)
        #pragma unroll
        for (int o = 0; o < FO; ++o) wm[c][o] = Wmix[(fg * 4 + c) * FO + o];
    float bm[FO];
    #pragma unroll
    for (int o = 0; o < FO; ++o) bm[o] = bmix[o];

    for (int tile = blockIdx.x; tile < NTILES; tile += gridDim.x) {
        const int n0 = tile * TN;
        GEMM_CORE_V3
        // epilogue: BN + ReLU + partial mix
        float p[8][FO];
        #pragma unroll
        for (int j = 0; j < 8; ++j) {
            float h0 = fmaxf(acc[j][0] * scv.x + shv.x, 0.0f);
            float h1 = fmaxf(acc[j][1] * scv.y + shv.y, 0.0f);
            float h2 = fmaxf(acc[j][2] * scv.z + shv.z, 0.0f);
            float h3 = fmaxf(acc[j][3] * scv.w + shv.w, 0.0f);
            #pragma unroll
            for (int o = 0; o < FO; ++o)
                p[j][o] = h0 * wm[0][o] + h1 * wm[1][o] + h2 * wm[2][o] + h3 * wm[3][o];
        }
        // reduce across the 16 fg lanes (lane bits 0..3)
        #pragma unroll
        for (int m = 1; m < 16; m <<= 1) {
            #pragma unroll
            for (int j = 0; j < 8; ++j)
                #pragma unroll
                for (int o = 0; o < FO; ++o)
                    p[j][o] += __shfl_xor(p[j][o], m);
        }
        if (fg == 0) {
            #pragma unroll
            for (int j = 0; j < 8; ++j) {
                int node = n0 + ng + 16 * j;
                if (node < NN) {
                    #pragma unroll
                    for (int o = 0; o < FO; ++o)
                        y[(size_t)node * FO + o] = p[j][o] + bm[o];
                }
            }
        }
    }
}

// ---------------- launch ----------------

extern "C" void kernel_launch(void* const* d_in, const int* in_sizes, int n_in,
                              void* d_out, int out_size, void* d_ws, size_t ws_size,
                              hipStream_t stream) {
    const float* x     = (const float*)d_in[0];
    const int*   edge  = (const int*)d_in[1];   // [2, NE]: row = edge, col = edge+NE
    const float* W1    = (const float*)d_in[2]; // [6,24,64]
    const float* b1    = (const float*)d_in[3];
    const float* gamma = (const float*)d_in[4];
    const float* beta  = (const float*)d_in[5];
    const float* Wmix  = (const float*)d_in[6]; // [1,64,6]
    const float* bmix  = (const float*)d_in[7];
    float* y = (float*)d_out;

    const int* row = edge;
    const int* col = edge + NE;

    // workspace layout (element offsets, 4B units)
    const size_t O_DEG   = 0;                        // NN
    const size_t O_DIS   = 500000;                   // NN
    const size_t O_RP    = 1000000;                  // NN+1 (padded)
    const size_t O_FILL  = 1500008;                  // NN
    const size_t O_PART  = 2000008;                  // 2048
    const size_t O_STATS = 2002056;                  // 128
    const size_t O_SS    = 2002184;                  // 128
    const size_t O_CSRC  = 2002312;                  // NE
    const size_t O_T     = 6002312;                  // 5 * NN*FI
    const size_t TOTAL_ELEMS = O_T + 5ull * NN * FI; // 66,002,312 -> 264 MB
    if (ws_size < TOTAL_ELEMS * 4ull) return;        // clean diagnostic bail

    float* wf = (float*)d_ws;
    int*   wi = (int*)d_ws;
    int*   deg   = wi + O_DEG;
    float* dis   = wf + O_DIS;
    int*   rp    = wi + O_RP;
    int*   fill  = wi + O_FILL;
    int*   part  = wi + O_PART;
    float* stats = wf + O_STATS;
    float* ss    = wf + O_SS;
    int*   csrc  = wi + O_CSRC;
    float* T1    = wf + O_T;
    float* T2    = T1 + (size_t)NN * FI;
    float* T3    = T2 + (size_t)NN * FI;
    float* T4    = T3 + (size_t)NN * FI;
    float* T5    = T4 + (size_t)NN * FI;

    hipMemsetAsync(deg,   0, NN * sizeof(int), stream);
    hipMemsetAsync(fill,  0, NN * sizeof(int), stream);
    hipMemsetAsync(stats, 0, 128 * sizeof(float), stream);

    const int BS = 256;
    k_deg<<<(NE + BS - 1) / BS, BS, 0, stream>>>(col, deg);
    k_dis<<<(NN + BS - 1) / BS, BS, 0, stream>>>(deg, dis);
    k_scanA<<<NBLK_SCAN, SCAN_BS, 0, stream>>>(deg, part);
    k_scanB<<<1, 256, 0, stream>>>(part, NBLK_SCAN);
    k_scanC<<<NBLK_SCAN, SCAN_BS, 0, stream>>>(deg, part, rp);
    k_fill<<<(NE + BS - 1) / BS, BS, 0, stream>>>(row, col, rp, fill, csrc);

    const int GPROP = (NN * 2 + BS - 1) / BS;   // 3907
    k_prop<true ><<<GPROP, BS, 0, stream>>>(rp, csrc, dis, x,  nullptr, T1);
    k_prop<false><<<GPROP, BS, 0, stream>>>(rp, csrc, dis, T1, x,  T2);
    k_prop<false><<<GPROP, BS, 0, stream>>>(rp, csrc, dis, T2, T1, T3);
    k_prop<false><<<GPROP, BS, 0, stream>>>(rp, csrc, dis, T3, T2, T4);
    k_prop<false><<<GPROP, BS, 0, stream>>>(rp, csrc, dis, T4, T3, T5);

    k_pass1<<<GEMM_GRID, 256, 0, stream>>>(x, T1, W1, b1, stats);
    k_finalize<<<1, 64, 0, stream>>>(stats, gamma, beta, ss);
    k_pass2<<<GEMM_GRID, 256, 0, stream>>>(x, T1, W1, b1, ss, Wmix, bmix, y);
}

// Round 6
// 1748.241 us; speedup vs baseline: 4.0627x; 1.0369x over previous
//
#include <hip/hip_runtime.h>
#include <hip/hip_fp16.h>

#define NN 500000
#define NE 4000000
#define FI 24
#define FH 64
#define KC 6
#define FO 6
#define BN_EPS 1e-5f

#define SCAN_BS 256
#define NBLK_SCAN ((NN + SCAN_BS - 1) / SCAN_BS)   // 1954

#define RH 32                                      // halfs per padded row (64B line)
#define TN 128                                     // nodes per GEMM tile
#define PADX 28                                    // Xs row stride (floats)
#define NTILES ((NN + TN - 1) / TN)                // 3907
#define GEMM_GRID 768

// ---------------- small helpers ----------------

// accumulate 8 halfs (one uint4) scaled by d into a[0..7]
__device__ __forceinline__ void acc8(float* a, float d, uint4 u) {
    const __half2* h2 = (const __half2*)&u;
    #pragma unroll
    for (int j = 0; j < 4; ++j) {
        float2 f = __half22float2(h2[j]);
        a[2 * j]     += d * f.x;
        a[2 * j + 1] += d * f.y;
    }
}

// pack 8 floats -> uint4 of halfs
__device__ __forceinline__ uint4 pack8(const float* a) {
    uint4 u;
    __half2* h2 = (__half2*)&u;
    #pragma unroll
    for (int j = 0; j < 4; ++j) h2[j] = __floats2half2_rn(a[2 * j], a[2 * j + 1]);
    return u;
}

// ---------------- degree ----------------

__global__ void k_deg(const int* __restrict__ col, int* __restrict__ deg) {
    int e = blockIdx.x * blockDim.x + threadIdx.x;
    if (e < NE) atomicAdd(&deg[col[e]], 1);
}

__global__ void k_dis(const int* __restrict__ deg, float* __restrict__ dis) {
    int i = blockIdx.x * blockDim.x + threadIdx.x;
    if (i < NN) {
        int d = deg[i];
        dis[i] = d > 0 ? rsqrtf((float)d) : 0.0f;
    }
}

// ---------------- x -> fp16 padded rows ----------------

__global__ void k_xhalf(const float* __restrict__ x, __half* __restrict__ Th0) {
    int n = blockIdx.x * blockDim.x + threadIdx.x;
    if (n >= NN) return;
    const float* r = x + (size_t)n * FI;
    float v[24];
    #pragma unroll
    for (int i = 0; i < 6; ++i) {
        float4 f = ((const float4*)r)[i];
        v[4 * i] = f.x; v[4 * i + 1] = f.y; v[4 * i + 2] = f.z; v[4 * i + 3] = f.w;
    }
    uint4* o = (uint4*)(Th0 + (size_t)n * RH);
    o[0] = pack8(v); o[1] = pack8(v + 8); o[2] = pack8(v + 16);
}

// ---------------- exclusive scan over deg -> rp (3 phase) ----------------

__global__ void k_scanA(const int* __restrict__ deg, int* __restrict__ partials) {
    __shared__ int lds[SCAN_BS];
    int i = blockIdx.x * SCAN_BS + threadIdx.x;
    lds[threadIdx.x] = (i < NN) ? deg[i] : 0;
    __syncthreads();
    for (int s = SCAN_BS / 2; s > 0; s >>= 1) {
        if (threadIdx.x < s) lds[threadIdx.x] += lds[threadIdx.x + s];
        __syncthreads();
    }
    if (threadIdx.x == 0) partials[blockIdx.x] = lds[0];
}

__global__ void k_scanB(int* __restrict__ partials, int n) {
    __shared__ int tsum[256];
    int vals[8];
    int base = threadIdx.x * 8;
    int acc = 0;
    #pragma unroll
    for (int j = 0; j < 8; ++j) {
        int idx = base + j;
        int v = (idx < n) ? partials[idx] : 0;
        vals[j] = acc;
        acc += v;
    }
    tsum[threadIdx.x] = acc;
    __syncthreads();
    int t = acc;
    for (int s = 1; s < 256; s <<= 1) {
        int other = (threadIdx.x >= (unsigned)s) ? tsum[threadIdx.x - s] : 0;
        __syncthreads();
        t += other;
        tsum[threadIdx.x] = t;
        __syncthreads();
    }
    int prefix = (threadIdx.x == 0) ? 0 : tsum[threadIdx.x - 1];
    #pragma unroll
    for (int j = 0; j < 8; ++j) {
        int idx = base + j;
        if (idx < n) partials[idx] = prefix + vals[j];
    }
}

__global__ void k_scanC(const int* __restrict__ deg, const int* __restrict__ partials,
                        int* __restrict__ rp) {
    __shared__ int lds[SCAN_BS];
    int i = blockIdx.x * SCAN_BS + threadIdx.x;
    int v = (i < NN) ? deg[i] : 0;
    lds[threadIdx.x] = v;
    __syncthreads();
    int t = v;
    for (int s = 1; s < SCAN_BS; s <<= 1) {
        int other = (threadIdx.x >= (unsigned)s) ? lds[threadIdx.x - s] : 0;
        __syncthreads();
        t += other;
        lds[threadIdx.x] = t;
        __syncthreads();
    }
    int excl = t - v + partials[blockIdx.x];
    if (i < NN) rp[i] = excl;
    if (i == NN - 1) rp[NN] = excl + v;   // total == NE
}

// ---------------- CSR fill ----------------

__global__ void k_fill(const int* __restrict__ row, const int* __restrict__ col,
                       const int* __restrict__ rp, int* __restrict__ fill,
                       int* __restrict__ csrc) {
    int e = blockIdx.x * blockDim.x + threadIdx.x;
    if (e >= NE) return;
    int r = row[e], c = col[e];
    int pos = rp[c] + atomicAdd(&fill[c], 1);
    csrc[pos] = r;
}

// ---------------- propagation (fp16 storage, fp32 math) ----------------
// Tout = (FIRST ? P : 2P - Tpp), P_c = -dis_c * sum_{e into c} dis_r * Tin[r]
// One thread per node; each neighbor row = one 64B line (3 uint4 loads).

template<bool FIRST>
__global__ __launch_bounds__(256) void k_prop(
    const int* __restrict__ rp, const int* __restrict__ csrc,
    const float* __restrict__ dis,
    const __half* __restrict__ Tin, const __half* __restrict__ Tpp,
    __half* __restrict__ Tout) {
    int n = blockIdx.x * 256 + threadIdx.x;
    if (n >= NN) return;
    int beg = rp[n], end = rp[n + 1];
    float a[24];
    #pragma unroll
    for (int j = 0; j < 24; ++j) a[j] = 0.0f;
    int i = beg;
    for (; i + 2 <= end; i += 2) {
        int s0 = csrc[i], s1 = csrc[i + 1];
        float d0 = dis[s0], d1 = dis[s1];
        const uint4* r0 = (const uint4*)(Tin + (size_t)s0 * RH);
        const uint4* r1 = (const uint4*)(Tin + (size_t)s1 * RH);
        uint4 u00 = r0[0], u01 = r0[1], u02 = r0[2];
        uint4 u10 = r1[0], u11 = r1[1], u12 = r1[2];
        acc8(a, d0, u00); acc8(a + 8, d0, u01); acc8(a + 16, d0, u02);
        acc8(a, d1, u10); acc8(a + 8, d1, u11); acc8(a + 16, d1, u12);
    }
    if (i < end) {
        int s0 = csrc[i];
        float d0 = dis[s0];
        const uint4* r0 = (const uint4*)(Tin + (size_t)s0 * RH);
        acc8(a, d0, r0[0]); acc8(a + 8, d0, r0[1]); acc8(a + 16, d0, r0[2]);
    }
    float m = FIRST ? -dis[n] : -2.0f * dis[n];
    if (FIRST) {
        #pragma unroll
        for (int j = 0; j < 24; ++j) a[j] *= m;
    } else {
        const uint4* pr = (const uint4*)(Tpp + (size_t)n * RH);
        uint4 p0 = pr[0], p1 = pr[1], p2 = pr[2];
        float pv[24];
        {
            const __half2* h2 = (const __half2*)&p0;
            #pragma unroll
            for (int j = 0; j < 4; ++j) { float2 f = __half22float2(h2[j]); pv[2*j] = f.x; pv[2*j+1] = f.y; }
        }
        {
            const __half2* h2 = (const __half2*)&p1;
            #pragma unroll
            for (int j = 0; j < 4; ++j) { float2 f = __half22float2(h2[j]); pv[8+2*j] = f.x; pv[8+2*j+1] = f.y; }
        }
        {
            const __half2* h2 = (const __half2*)&p2;
            #pragma unroll
            for (int j = 0; j < 4; ++j) { float2 f = __half22float2(h2[j]); pv[16+2*j] = f.x; pv[16+2*j+1] = f.y; }
        }
        #pragma unroll
        for (int j = 0; j < 24; ++j) a[j] = m * a[j] - pv[j];
    }
    uint4* o = (uint4*)(Tout + (size_t)n * RH);
    o[0] = pack8(a); o[1] = pack8(a + 8); o[2] = pack8(a + 16);
}

// ---------------- tiled GEMM core (round-3 structure, fp16 staging) ----------------
// Block 256 thr; tile 128 nodes x 64 feats; thread (ng=tid>>4, fg=tid&15) owns
// nodes {ng+16j, j<8} x feats {fg*4..+3}. Xs (fp32) staged from fp16 rows.
// 384 real chunks (128 rows x 3 uint4); thread t handles chunk t and t+256.

#define GEMM_CORE_H                                                                 \
    float acc[8][4];                                                                \
    _Pragma("unroll")                                                               \
    for (int j = 0; j < 8; ++j) {                                                   \
        acc[j][0] = bb.x; acc[j][1] = bb.y; acc[j][2] = bb.z; acc[j][3] = bb.w;     \
    }                                                                               \
    for (int seg = 0; seg < KC; ++seg) {                                            \
        const __half* hsrc = Th + (size_t)seg * ((size_t)NN * RH);                  \
        __syncthreads();                                                            \
        _Pragma("unroll")                                                           \
        for (int c = 0; c < 2; ++c) {                                               \
            int cid = threadIdx.x + c * 256;                                        \
            if (c == 0 || threadIdx.x < 128) {                                      \
                int rw = cid / 3, sb = cid - rw * 3;                                \
                uint4 u = make_uint4(0, 0, 0, 0);                                   \
                if (n0 + rw < NN)                                                   \
                    u = ((const uint4*)(hsrc + (size_t)(n0 + rw) * RH))[sb];        \
                const __half2* h2 = (const __half2*)&u;                             \
                float2 f0 = __half22float2(h2[0]);                                  \
                float2 f1 = __half22float2(h2[1]);                                  \
                float2 f2 = __half22float2(h2[2]);                                  \
                float2 f3 = __half22float2(h2[3]);                                  \
                *(float4*)&Xs[rw * PADX + sb * 8]     = make_float4(f0.x, f0.y, f1.x, f1.y); \
                *(float4*)&Xs[rw * PADX + sb * 8 + 4] = make_float4(f2.x, f2.y, f3.x, f3.y); \
            }                                                                       \
        }                                                                           \
        __syncthreads();                                                            \
        _Pragma("unroll")                                                           \
        for (int g = 0; g < 6; ++g) {                                               \
            const int kk = g * 4;                                                   \
            float4 w0 = *(const float4*)&Wl[(seg * 24 + kk + 0) * FH + fg * 4];     \
            float4 w1 = *(const float4*)&Wl[(seg * 24 + kk + 1) * FH + fg * 4];     \
            float4 w2 = *(const float4*)&Wl[(seg * 24 + kk + 2) * FH + fg * 4];     \
            float4 w3 = *(const float4*)&Wl[(seg * 24 + kk + 3) * FH + fg * 4];     \
            _Pragma("unroll")                                                       \
            for (int j = 0; j < 8; ++j) {                                           \
                float4 xv = *(const float4*)&Xs[(ng + 16 * j) * PADX + kk];         \
                acc[j][0] += xv.x * w0.x + xv.y * w1.x + xv.z * w2.x + xv.w * w3.x; \
                acc[j][1] += xv.x * w0.y + xv.y * w1.y + xv.z * w2.y + xv.w * w3.y; \
                acc[j][2] += xv.x * w0.z + xv.y * w1.z + xv.z * w2.z + xv.w * w3.z; \
                acc[j][3] += xv.x * w0.w + xv.y * w1.w + xv.z * w2.w + xv.w * w3.w; \
            }                                                                       \
        }                                                                           \
    }

// ---------------- pass 1: BN stats of h (h not stored) ----------------

__global__ __launch_bounds__(256) void k_pass1(
    const __half* __restrict__ Th,
    const float* __restrict__ W1, const float* __restrict__ b1,
    float* __restrict__ stats) {
    __shared__ float Wl[KC * FI * FH];   // 36 KiB
    __shared__ float Xs[TN * PADX];      // 14 KiB
    __shared__ float st[2 * FH];
    {
        const float4* src = (const float4*)W1;
        float4* dst = (float4*)Wl;
        for (int i = threadIdx.x; i < KC * FI * FH / 4; i += 256) dst[i] = src[i];
    }
    if (threadIdx.x < 2 * FH) st[threadIdx.x] = 0.0f;
    __syncthreads();
    const int fg = threadIdx.x & 15;
    const int ng = threadIdx.x >> 4;
    const float4 bb = *(const float4*)&b1[fg * 4];
    float ssum[4] = {0, 0, 0, 0}, sqsum[4] = {0, 0, 0, 0};
    for (int tile = blockIdx.x; tile < NTILES; tile += gridDim.x) {
        const int n0 = tile * TN;
        GEMM_CORE_H
        #pragma unroll
        for (int j = 0; j < 8; ++j) {
            if (n0 + ng + 16 * j < NN) {
                #pragma unroll
                for (int c = 0; c < 4; ++c) {
                    float v = acc[j][c];
                    ssum[c] += v;
                    sqsum[c] += v * v;
                }
            }
        }
    }
    #pragma unroll
    for (int c = 0; c < 4; ++c) {
        atomicAdd(&st[fg * 4 + c], ssum[c]);
        atomicAdd(&st[FH + fg * 4 + c], sqsum[c]);
    }
    __syncthreads();
    if (threadIdx.x < 2 * FH) atomicAdd(&stats[threadIdx.x], st[threadIdx.x]);
}

// ---------------- BN finalize ----------------

__global__ void k_finalize(const float* __restrict__ stats, const float* __restrict__ gamma,
                           const float* __restrict__ beta, float* __restrict__ ss) {
    int f = threadIdx.x;
    if (f < FH) {
        float mean = stats[f] * (1.0f / NN);
        float var  = stats[f + FH] * (1.0f / NN) - mean * mean;
        float rstd = rsqrtf(var + BN_EPS);
        float sc = gamma[f] * rstd;
        ss[f] = sc;
        ss[f + FH] = beta[f] - mean * sc;
    }
}

// ---------------- pass 2: recompute h, fused BN+ReLU+mix -> y ----------------

__global__ __launch_bounds__(256) void k_pass2(
    const __half* __restrict__ Th,
    const float* __restrict__ W1, const float* __restrict__ b1,
    const float* __restrict__ ss,
    const float* __restrict__ Wmix, const float* __restrict__ bmix,
    float* __restrict__ y) {
    __shared__ float Wl[KC * FI * FH];
    __shared__ float Xs[TN * PADX];
    {
        const float4* src = (const float4*)W1;
        float4* dst = (float4*)Wl;
        for (int i = threadIdx.x; i < KC * FI * FH / 4; i += 256) dst[i] = src[i];
    }
    __syncthreads();
    const int fg = threadIdx.x & 15;
    const int ng = threadIdx.x >> 4;
    const float4 bb  = *(const float4*)&b1[fg * 4];
    const float4 scv = *(const float4*)&ss[fg * 4];
    const float4 shv = *(const float4*)&ss[FH + fg * 4];
    float wm[4][FO];
    #pragma unroll
    for (int c = 0; c < 4; ++c)
        #pragma unroll
        for (int o = 0; o < FO; ++o) wm[c][o] = Wmix[(fg * 4 + c) * FO + o];
    float bm[FO];
    #pragma unroll
    for (int o = 0; o < FO; ++o) bm[o] = bmix[o];

    for (int tile = blockIdx.x; tile < NTILES; tile += gridDim.x) {
        const int n0 = tile * TN;
        GEMM_CORE_H
        // epilogue: BN + ReLU + partial mix
        float p[8][FO];
        #pragma unroll
        for (int j = 0; j < 8; ++j) {
            float h0 = fmaxf(acc[j][0] * scv.x + shv.x, 0.0f);
            float h1 = fmaxf(acc[j][1] * scv.y + shv.y, 0.0f);
            float h2 = fmaxf(acc[j][2] * scv.z + shv.z, 0.0f);
            float h3 = fmaxf(acc[j][3] * scv.w + shv.w, 0.0f);
            #pragma unroll
            for (int o = 0; o < FO; ++o)
                p[j][o] = h0 * wm[0][o] + h1 * wm[1][o] + h2 * wm[2][o] + h3 * wm[3][o];
        }
        #pragma unroll
        for (int m = 1; m < 16; m <<= 1) {
            #pragma unroll
            for (int j = 0; j < 8; ++j)
                #pragma unroll
                for (int o = 0; o < FO; ++o)
                    p[j][o] += __shfl_xor(p[j][o], m);
        }
        if (fg == 0) {
            #pragma unroll
            for (int j = 0; j < 8; ++j) {
                int node = n0 + ng + 16 * j;
                if (node < NN) {
                    #pragma unroll
                    for (int o = 0; o < FO; ++o)
                        y[(size_t)node * FO + o] = p[j][o] + bm[o];
                }
            }
        }
    }
}

// ---------------- launch ----------------

extern "C" void kernel_launch(void* const* d_in, const int* in_sizes, int n_in,
                              void* d_out, int out_size, void* d_ws, size_t ws_size,
                              hipStream_t stream) {
    const float* x     = (const float*)d_in[0];
    const int*   edge  = (const int*)d_in[1];   // [2, NE]: row = edge, col = edge+NE
    const float* W1    = (const float*)d_in[2]; // [6,24,64]
    const float* b1    = (const float*)d_in[3];
    const float* gamma = (const float*)d_in[4];
    const float* beta  = (const float*)d_in[5];
    const float* Wmix  = (const float*)d_in[6]; // [1,64,6]
    const float* bmix  = (const float*)d_in[7];
    float* y = (float*)d_out;

    const int* row = edge;
    const int* col = edge + NE;

    // workspace layout (element offsets, 4B units)
    const size_t O_DEG   = 0;                        // NN
    const size_t O_DIS   = 500000;                   // NN
    const size_t O_RP    = 1000000;                  // NN+1 (padded)
    const size_t O_FILL  = 1500008;                  // NN
    const size_t O_PART  = 2000008;                  // 2048
    const size_t O_STATS = 2002056;                  // 128
    const size_t O_SS    = 2002184;                  // 128
    const size_t O_CSRC  = 2002312;                  // NE
    const size_t O_TH    = 6002312;                  // 6 * NN * RH halfs = 48,000,000 float-units
    const size_t TOTAL_ELEMS = O_TH + 6ull * NN * RH / 2;  // 54,002,312 -> 216 MB
    if (ws_size < TOTAL_ELEMS * 4ull) return;        // clean diagnostic bail

    float* wf = (float*)d_ws;
    int*   wi = (int*)d_ws;
    int*   deg   = wi + O_DEG;
    float* dis   = wf + O_DIS;
    int*   rp    = wi + O_RP;
    int*   fill  = wi + O_FILL;
    int*   part  = wi + O_PART;
    float* stats = wf + O_STATS;
    float* ss    = wf + O_SS;
    int*   csrc  = wi + O_CSRC;
    __half* Th   = (__half*)(wf + O_TH);             // 6 levels: x,T1..T5
    __half* Th0  = Th;
    __half* Th1  = Th + 1ull * NN * RH;
    __half* Th2  = Th + 2ull * NN * RH;
    __half* Th3  = Th + 3ull * NN * RH;
    __half* Th4  = Th + 4ull * NN * RH;
    __half* Th5  = Th + 5ull * NN * RH;

    hipMemsetAsync(deg,   0, NN * sizeof(int), stream);
    hipMemsetAsync(fill,  0, NN * sizeof(int), stream);
    hipMemsetAsync(stats, 0, 128 * sizeof(float), stream);

    const int BS = 256;
    const int GN = (NN + BS - 1) / BS;   // 1954
    k_deg<<<(NE + BS - 1) / BS, BS, 0, stream>>>(col, deg);
    k_dis<<<GN, BS, 0, stream>>>(deg, dis);
    k_xhalf<<<GN, BS, 0, stream>>>(x, Th0);
    k_scanA<<<NBLK_SCAN, SCAN_BS, 0, stream>>>(deg, part);
    k_scanB<<<1, 256, 0, stream>>>(part, NBLK_SCAN);
    k_scanC<<<NBLK_SCAN, SCAN_BS, 0, stream>>>(deg, part, rp);
    k_fill<<<(NE + BS - 1) / BS, BS, 0, stream>>>(row, col, rp, fill, csrc);

    k_prop<true ><<<GN, BS, 0, stream>>>(rp, csrc, dis, Th0, nullptr, Th1);
    k_prop<false><<<GN, BS, 0, stream>>>(rp, csrc, dis, Th1, Th0, Th2);
    k_prop<false><<<GN, BS, 0, stream>>>(rp, csrc, dis, Th2, Th1, Th3);
    k_prop<false><<<GN, BS, 0, stream>>>(rp, csrc, dis, Th3, Th2, Th4);
    k_prop<false><<<GN, BS, 0, stream>>>(rp, csrc, dis, Th4, Th3, Th5);

    k_pass1<<<GEMM_GRID, 256, 0, stream>>>(Th, W1, b1, stats);
    k_finalize<<<1, 64, 0, stream>>>(stats, gamma, beta, ss);
    k_pass2<<<GEMM_GRID, 256, 0, stream>>>(Th, W1, b1, ss, Wmix, bmix, y);
}

// Round 7
// 1388.755 us; speedup vs baseline: 5.1144x; 1.2589x over previous
//
#include <hip/hip_runtime.h>
#include <hip/hip_fp16.h>

#define NN 500000
#define NE 4000000
#define FI 24
#define FH 64
#define KC 6
#define FO 6
#define BN_EPS 1e-5f

#define SCAN_BS 256
#define NBLK_SCAN ((NN + SCAN_BS - 1) / SCAN_BS)   // 1954

#define RH 32                                      // halfs per padded row (64B line)
#define NMT (NN / 16)                              // 31250 M-tiles (exact)
#define PASS_GRID 1024

typedef _Float16 half8 __attribute__((ext_vector_type(8)));
typedef float f32x4 __attribute__((ext_vector_type(4)));
union U4H8 { uint4 u; half8 h; };

// ---------------- small helpers ----------------

__device__ __forceinline__ void acc8(float* a, float d, uint4 u) {
    const __half2* h2 = (const __half2*)&u;
    #pragma unroll
    for (int j = 0; j < 4; ++j) {
        float2 f = __half22float2(h2[j]);
        a[2 * j]     += d * f.x;
        a[2 * j + 1] += d * f.y;
    }
}

__device__ __forceinline__ uint4 pack8(const float* a) {
    uint4 u;
    __half2* h2 = (__half2*)&u;
    #pragma unroll
    for (int j = 0; j < 4; ++j) h2[j] = __floats2half2_rn(a[2 * j], a[2 * j + 1]);
    return u;
}

// ---------------- degree ----------------

__global__ void k_deg(const int* __restrict__ col, int* __restrict__ deg) {
    int e = blockIdx.x * blockDim.x + threadIdx.x;
    if (e < NE) atomicAdd(&deg[col[e]], 1);
}

__global__ void k_dis(const int* __restrict__ deg, float* __restrict__ dis) {
    int i = blockIdx.x * blockDim.x + threadIdx.x;
    if (i < NN) {
        int d = deg[i];
        dis[i] = d > 0 ? rsqrtf((float)d) : 0.0f;
    }
}

// ---------------- x -> fp16 padded rows ----------------

__global__ void k_xhalf(const float* __restrict__ x, __half* __restrict__ Th0) {
    int n = blockIdx.x * blockDim.x + threadIdx.x;
    if (n >= NN) return;
    const float* r = x + (size_t)n * FI;
    float v[24];
    #pragma unroll
    for (int i = 0; i < 6; ++i) {
        float4 f = ((const float4*)r)[i];
        v[4 * i] = f.x; v[4 * i + 1] = f.y; v[4 * i + 2] = f.z; v[4 * i + 3] = f.w;
    }
    uint4* o = (uint4*)(Th0 + (size_t)n * RH);
    o[0] = pack8(v); o[1] = pack8(v + 8); o[2] = pack8(v + 16);
    o[3] = make_uint4(0, 0, 0, 0);   // zero the pad (halfs 24..31)
}

// ---------------- exclusive scan over deg -> rp (3 phase) ----------------

__global__ void k_scanA(const int* __restrict__ deg, int* __restrict__ partials) {
    __shared__ int lds[SCAN_BS];
    int i = blockIdx.x * SCAN_BS + threadIdx.x;
    lds[threadIdx.x] = (i < NN) ? deg[i] : 0;
    __syncthreads();
    for (int s = SCAN_BS / 2; s > 0; s >>= 1) {
        if (threadIdx.x < s) lds[threadIdx.x] += lds[threadIdx.x + s];
        __syncthreads();
    }
    if (threadIdx.x == 0) partials[blockIdx.x] = lds[0];
}

__global__ void k_scanB(int* __restrict__ partials, int n) {
    __shared__ int tsum[256];
    int vals[8];
    int base = threadIdx.x * 8;
    int acc = 0;
    #pragma unroll
    for (int j = 0; j < 8; ++j) {
        int idx = base + j;
        int v = (idx < n) ? partials[idx] : 0;
        vals[j] = acc;
        acc += v;
    }
    tsum[threadIdx.x] = acc;
    __syncthreads();
    int t = acc;
    for (int s = 1; s < 256; s <<= 1) {
        int other = (threadIdx.x >= (unsigned)s) ? tsum[threadIdx.x - s] : 0;
        __syncthreads();
        t += other;
        tsum[threadIdx.x] = t;
        __syncthreads();
    }
    int prefix = (threadIdx.x == 0) ? 0 : tsum[threadIdx.x - 1];
    #pragma unroll
    for (int j = 0; j < 8; ++j) {
        int idx = base + j;
        if (idx < n) partials[idx] = prefix + vals[j];
    }
}

__global__ void k_scanC(const int* __restrict__ deg, const int* __restrict__ partials,
                        int* __restrict__ rp) {
    __shared__ int lds[SCAN_BS];
    int i = blockIdx.x * SCAN_BS + threadIdx.x;
    int v = (i < NN) ? deg[i] : 0;
    lds[threadIdx.x] = v;
    __syncthreads();
    int t = v;
    for (int s = 1; s < SCAN_BS; s <<= 1) {
        int other = (threadIdx.x >= (unsigned)s) ? lds[threadIdx.x - s] : 0;
        __syncthreads();
        t += other;
        lds[threadIdx.x] = t;
        __syncthreads();
    }
    int excl = t - v + partials[blockIdx.x];
    if (i < NN) rp[i] = excl;
    if (i == NN - 1) rp[NN] = excl + v;   // total == NE
}

// ---------------- CSR fill ----------------

__global__ void k_fill(const int* __restrict__ row, const int* __restrict__ col,
                       const int* __restrict__ rp, int* __restrict__ fill,
                       int* __restrict__ csrc) {
    int e = blockIdx.x * blockDim.x + threadIdx.x;
    if (e >= NE) return;
    int r = row[e], c = col[e];
    int pos = rp[c] + atomicAdd(&fill[c], 1);
    csrc[pos] = r;
}

// ---------------- propagation (fp16 storage, fp32 math) — unchanged from R6 ----------------

template<bool FIRST>
__global__ __launch_bounds__(256) void k_prop(
    const int* __restrict__ rp, const int* __restrict__ csrc,
    const float* __restrict__ dis,
    const __half* __restrict__ Tin, const __half* __restrict__ Tpp,
    __half* __restrict__ Tout) {
    int n = blockIdx.x * 256 + threadIdx.x;
    if (n >= NN) return;
    int beg = rp[n], end = rp[n + 1];
    float a[24];
    #pragma unroll
    for (int j = 0; j < 24; ++j) a[j] = 0.0f;
    int i = beg;
    for (; i + 2 <= end; i += 2) {
        int s0 = csrc[i], s1 = csrc[i + 1];
        float d0 = dis[s0], d1 = dis[s1];
        const uint4* r0 = (const uint4*)(Tin + (size_t)s0 * RH);
        const uint4* r1 = (const uint4*)(Tin + (size_t)s1 * RH);
        uint4 u00 = r0[0], u01 = r0[1], u02 = r0[2];
        uint4 u10 = r1[0], u11 = r1[1], u12 = r1[2];
        acc8(a, d0, u00); acc8(a + 8, d0, u01); acc8(a + 16, d0, u02);
        acc8(a, d1, u10); acc8(a + 8, d1, u11); acc8(a + 16, d1, u12);
    }
    if (i < end) {
        int s0 = csrc[i];
        float d0 = dis[s0];
        const uint4* r0 = (const uint4*)(Tin + (size_t)s0 * RH);
        acc8(a, d0, r0[0]); acc8(a + 8, d0, r0[1]); acc8(a + 16, d0, r0[2]);
    }
    float m = FIRST ? -dis[n] : -2.0f * dis[n];
    if (FIRST) {
        #pragma unroll
        for (int j = 0; j < 24; ++j) a[j] *= m;
    } else {
        const uint4* pr = (const uint4*)(Tpp + (size_t)n * RH);
        uint4 p0 = pr[0], p1 = pr[1], p2 = pr[2];
        float pv[24];
        {
            const __half2* h2 = (const __half2*)&p0;
            #pragma unroll
            for (int j = 0; j < 4; ++j) { float2 f = __half22float2(h2[j]); pv[2*j] = f.x; pv[2*j+1] = f.y; }
        }
        {
            const __half2* h2 = (const __half2*)&p1;
            #pragma unroll
            for (int j = 0; j < 4; ++j) { float2 f = __half22float2(h2[j]); pv[8+2*j] = f.x; pv[8+2*j+1] = f.y; }
        }
        {
            const __half2* h2 = (const __half2*)&p2;
            #pragma unroll
            for (int j = 0; j < 4; ++j) { float2 f = __half22float2(h2[j]); pv[16+2*j] = f.x; pv[16+2*j+1] = f.y; }
        }
        #pragma unroll
        for (int j = 0; j < 24; ++j) a[j] = m * a[j] - pv[j];
    }
    uint4* o = (uint4*)(Tout + (size_t)n * RH);
    o[0] = pack8(a); o[1] = pack8(a + 8); o[2] = pack8(a + 16);
    o[3] = make_uint4(0, 0, 0, 0);   // keep pad zeroed for MFMA A-frags
}

// ---------------- MFMA pass kernels ----------------
// h[n0..n0+15][0..63] = sum_seg A_seg @ B_seg, A from Th (K=32 = one padded row),
// B = fp16 W fragments in LDS (k>=24 zero).
// Layouts (guide-verified): A[m=lane&15][k=quad*8+j]; B[k=quad*8+j][n=lane&15];
// D: col n = lane&15, row m = quad*4 + reg.

__device__ __forceinline__ void build_bfrags(const float* __restrict__ W1, uint4* Bf) {
    for (int s = threadIdx.x; s < KC * 4 * 64; s += 256) {
        int lane = s & 63, blk = s >> 6;
        int seg = blk >> 2, nb = blk & 3;
        int q = lane >> 4, n = lane & 15;
        float v[8];
        #pragma unroll
        for (int j = 0; j < 8; ++j) {
            int k = q * 8 + j;
            v[j] = (k < FI) ? W1[(seg * FI + k) * FH + nb * 16 + n] : 0.0f;
        }
        U4H8 u;
        __half2* h2 = (__half2*)&u;
        #pragma unroll
        for (int j = 0; j < 4; ++j) h2[j] = __floats2half2_rn(v[2 * j], v[2 * j + 1]);
        Bf[s] = u.u;
    }
}

__global__ __launch_bounds__(256) void k_pass1(
    const __half* __restrict__ Th, const float* __restrict__ W1,
    const float* __restrict__ b1, float* __restrict__ stats) {
    __shared__ uint4 Bf[KC * 4 * 64];   // 24 KiB
    __shared__ float st[2 * FH];
    build_bfrags(W1, Bf);
    if (threadIdx.x < 2 * FH) st[threadIdx.x] = 0.0f;
    __syncthreads();
    const int lane = threadIdx.x & 63;
    const int q = lane >> 4, ln = lane & 15;
    const int wid = blockIdx.x * 4 + (threadIdx.x >> 6);
    const int nw = gridDim.x * 4;
    float bias[4];
    #pragma unroll
    for (int nb = 0; nb < 4; ++nb) bias[nb] = b1[nb * 16 + ln];
    float ssum[4] = {0, 0, 0, 0}, sqsum[4] = {0, 0, 0, 0};
    for (int t = wid; t < NMT; t += nw) {
        const int n0 = t * 16;
        f32x4 acc[4];
        #pragma unroll
        for (int nb = 0; nb < 4; ++nb)
            acc[nb] = (f32x4){bias[nb], bias[nb], bias[nb], bias[nb]};
        #pragma unroll
        for (int seg = 0; seg < KC; ++seg) {
            U4H8 a;
            a.u = *(const uint4*)(Th + (size_t)seg * ((size_t)NN * RH)
                                  + (size_t)(n0 + ln) * RH + q * 8);
            #pragma unroll
            for (int nb = 0; nb < 4; ++nb) {
                U4H8 b; b.u = Bf[(seg * 4 + nb) * 64 + lane];
                acc[nb] = __builtin_amdgcn_mfma_f32_16x16x32_f16(a.h, b.h, acc[nb], 0, 0, 0);
            }
        }
        #pragma unroll
        for (int nb = 0; nb < 4; ++nb) {
            #pragma unroll
            for (int r = 0; r < 4; ++r) {
                float v = acc[nb][r];
                ssum[nb] += v;
                sqsum[nb] += v * v;
            }
        }
    }
    #pragma unroll
    for (int nb = 0; nb < 4; ++nb) {
        ssum[nb]  += __shfl_xor(ssum[nb], 16);  ssum[nb]  += __shfl_xor(ssum[nb], 32);
        sqsum[nb] += __shfl_xor(sqsum[nb], 16); sqsum[nb] += __shfl_xor(sqsum[nb], 32);
    }
    if (lane < 16) {
        #pragma unroll
        for (int nb = 0; nb < 4; ++nb) {
            atomicAdd(&st[nb * 16 + ln], ssum[nb]);
            atomicAdd(&st[FH + nb * 16 + ln], sqsum[nb]);
        }
    }
    __syncthreads();
    if (threadIdx.x < 2 * FH) atomicAdd(&stats[threadIdx.x], st[threadIdx.x]);
}

__global__ void k_finalize(const float* __restrict__ stats, const float* __restrict__ gamma,
                           const float* __restrict__ beta, float* __restrict__ ss) {
    int f = threadIdx.x;
    if (f < FH) {
        float mean = stats[f] * (1.0f / NN);
        float var  = stats[f + FH] * (1.0f / NN) - mean * mean;
        float rstd = rsqrtf(var + BN_EPS);
        float sc = gamma[f] * rstd;
        ss[f] = sc;
        ss[f + FH] = beta[f] - mean * sc;
    }
}

__global__ __launch_bounds__(256) void k_pass2(
    const __half* __restrict__ Th, const float* __restrict__ W1,
    const float* __restrict__ b1, const float* __restrict__ ss,
    const float* __restrict__ Wmix, const float* __restrict__ bmix,
    float* __restrict__ y) {
    __shared__ uint4 Bf[KC * 4 * 64];
    build_bfrags(W1, Bf);
    __syncthreads();
    const int lane = threadIdx.x & 63;
    const int q = lane >> 4, ln = lane & 15;
    const int wid = blockIdx.x * 4 + (threadIdx.x >> 6);
    const int nw = gridDim.x * 4;
    float bias[4], sc[4], sh[4], wm[4][FO];
    #pragma unroll
    for (int nb = 0; nb < 4; ++nb) {
        int f = nb * 16 + ln;
        bias[nb] = b1[f];
        sc[nb] = ss[f];
        sh[nb] = ss[FH + f];
        #pragma unroll
        for (int o = 0; o < FO; ++o) wm[nb][o] = Wmix[f * FO + o];
    }
    float bm[FO];
    #pragma unroll
    for (int o = 0; o < FO; ++o) bm[o] = bmix[o];

    for (int t = wid; t < NMT; t += nw) {
        const int n0 = t * 16;
        f32x4 acc[4];
        #pragma unroll
        for (int nb = 0; nb < 4; ++nb)
            acc[nb] = (f32x4){bias[nb], bias[nb], bias[nb], bias[nb]};
        #pragma unroll
        for (int seg = 0; seg < KC; ++seg) {
            U4H8 a;
            a.u = *(const uint4*)(Th + (size_t)seg * ((size_t)NN * RH)
                                  + (size_t)(n0 + ln) * RH + q * 8);
            #pragma unroll
            for (int nb = 0; nb < 4; ++nb) {
                U4H8 b; b.u = Bf[(seg * 4 + nb) * 64 + lane];
                acc[nb] = __builtin_amdgcn_mfma_f32_16x16x32_f16(a.h, b.h, acc[nb], 0, 0, 0);
            }
        }
        // BN + ReLU + mix partials (lane holds feature nb*16+ln, rows q*4+r)
        float p[4][FO];
        #pragma unroll
        for (int r = 0; r < 4; ++r)
            #pragma unroll
            for (int o = 0; o < FO; ++o) p[r][o] = 0.0f;
        #pragma unroll
        for (int nb = 0; nb < 4; ++nb) {
            #pragma unroll
            for (int r = 0; r < 4; ++r) {
                float hv = fmaxf(acc[nb][r] * sc[nb] + sh[nb], 0.0f);
                #pragma unroll
                for (int o = 0; o < FO; ++o) p[r][o] += hv * wm[nb][o];
            }
        }
        // reduce over the 16 feature-lanes within each quad
        #pragma unroll
        for (int m = 1; m < 16; m <<= 1) {
            #pragma unroll
            for (int r = 0; r < 4; ++r)
                #pragma unroll
                for (int o = 0; o < FO; ++o)
                    p[r][o] += __shfl_xor(p[r][o], m);
        }
        if (ln == 0) {
            #pragma unroll
            for (int r = 0; r < 4; ++r) {
                int node = n0 + q * 4 + r;
                #pragma unroll
                for (int o = 0; o < FO; ++o)
                    y[(size_t)node * FO + o] = p[r][o] + bm[o];
            }
        }
    }
}

// ---------------- launch ----------------

extern "C" void kernel_launch(void* const* d_in, const int* in_sizes, int n_in,
                              void* d_out, int out_size, void* d_ws, size_t ws_size,
                              hipStream_t stream) {
    const float* x     = (const float*)d_in[0];
    const int*   edge  = (const int*)d_in[1];   // [2, NE]: row = edge, col = edge+NE
    const float* W1    = (const float*)d_in[2]; // [6,24,64]
    const float* b1    = (const float*)d_in[3];
    const float* gamma = (const float*)d_in[4];
    const float* beta  = (const float*)d_in[5];
    const float* Wmix  = (const float*)d_in[6]; // [1,64,6]
    const float* bmix  = (const float*)d_in[7];
    float* y = (float*)d_out;

    const int* row = edge;
    const int* col = edge + NE;

    // workspace layout (element offsets, 4B units)
    const size_t O_DEG   = 0;                        // NN
    const size_t O_DIS   = 500000;                   // NN
    const size_t O_RP    = 1000000;                  // NN+1 (padded)
    const size_t O_FILL  = 1500008;                  // NN
    const size_t O_PART  = 2000008;                  // 2048
    const size_t O_STATS = 2002056;                  // 128
    const size_t O_SS    = 2002184;                  // 128
    const size_t O_CSRC  = 2002312;                  // NE
    const size_t O_TH    = 6002312;                  // 6 * NN * RH halfs
    const size_t TOTAL_ELEMS = O_TH + 6ull * NN * RH / 2;  // 216 MB
    if (ws_size < TOTAL_ELEMS * 4ull) return;        // clean diagnostic bail

    float* wf = (float*)d_ws;
    int*   wi = (int*)d_ws;
    int*   deg   = wi + O_DEG;
    float* dis   = wf + O_DIS;
    int*   rp    = wi + O_RP;
    int*   fill  = wi + O_FILL;
    int*   part  = wi + O_PART;
    float* stats = wf + O_STATS;
    float* ss    = wf + O_SS;
    int*   csrc  = wi + O_CSRC;
    __half* Th   = (__half*)(wf + O_TH);             // 6 levels: x,T1..T5
    __half* Th0  = Th;
    __half* Th1  = Th + 1ull * NN * RH;
    __half* Th2  = Th + 2ull * NN * RH;
    __half* Th3  = Th + 3ull * NN * RH;
    __half* Th4  = Th + 4ull * NN * RH;
    __half* Th5  = Th + 5ull * NN * RH;

    hipMemsetAsync(deg,   0, NN * sizeof(int), stream);
    hipMemsetAsync(fill,  0, NN * sizeof(int), stream);
    hipMemsetAsync(stats, 0, 128 * sizeof(float), stream);

    const int BS = 256;
    const int GN = (NN + BS - 1) / BS;   // 1954
    k_deg<<<(NE + BS - 1) / BS, BS, 0, stream>>>(col, deg);
    k_dis<<<GN, BS, 0, stream>>>(deg, dis);
    k_xhalf<<<GN, BS, 0, stream>>>(x, Th0);
    k_scanA<<<NBLK_SCAN, SCAN_BS, 0, stream>>>(deg, part);
    k_scanB<<<1, 256, 0, stream>>>(part, NBLK_SCAN);
    k_scanC<<<NBLK_SCAN, SCAN_BS, 0, stream>>>(deg, part, rp);
    k_fill<<<(NE + BS - 1) / BS, BS, 0, stream>>>(row, col, rp, fill, csrc);

    k_prop<true ><<<GN, BS, 0, stream>>>(rp, csrc, dis, Th0, nullptr, Th1);
    k_prop<false><<<GN, BS, 0, stream>>>(rp, csrc, dis, Th1, Th0, Th2);
    k_prop<false><<<GN, BS, 0, stream>>>(rp, csrc, dis, Th2, Th1, Th3);
    k_prop<false><<<GN, BS, 0, stream>>>(rp, csrc, dis, Th3, Th2, Th4);
    k_prop<false><<<GN, BS, 0, stream>>>(rp, csrc, dis, Th4, Th3, Th5);

    k_pass1<<<PASS_GRID, 256, 0, stream>>>(Th, W1, b1, stats);
    k_finalize<<<1, 64, 0, stream>>>(stats, gamma, beta, ss);
    k_pass2<<<PASS_GRID, 256, 0, stream>>>(Th, W1, b1, ss, Wmix, bmix, y);
}